// Round 1
// baseline (124.701 us; speedup 1.0000x reference)
//
#include <hip/hip_runtime.h>

#define EPS 1e-5f
constexpr int B = 4, C = 64, H = 128, W = 256;
constexpr int Hg = 512, Wg = 1024;
constexpr int NC = 19;
constexpr int HW = H * W;          // 32768 pixels per (b,c) plane

// ---------------- K1: downsample gt (nearest, stride 4) + per-(b,cid) counts --------
__global__ __launch_bounds__(256) void k_downsample(const int* __restrict__ gt,
                                                    int* __restrict__ gt_r,
                                                    int* __restrict__ counts) {
  __shared__ int hist[NC];
  int t = threadIdx.x;            // w in [0,256)
  if (t < NC) hist[t] = 0;
  __syncthreads();
  int blk = blockIdx.x;           // b*H + h, 512 blocks
  int b = blk >> 7;
  int h = blk & (H - 1);
  int cls = gt[(size_t)(b * Hg + h * 4) * Wg + t * 4];
  gt_r[blk * W + t] = cls;
  if ((unsigned)cls < (unsigned)NC) atomicAdd(&hist[cls], 1);
  __syncthreads();
  if (t < NC && hist[t] != 0) atomicAdd(&counts[b * NC + t], hist[t]);
}

// ---------------- K2: per-(b,c) plane, per-class sum / sumsq ------------------------
// Per-thread LDS accumulators acc[cls*256 + tid]: bank = tid%32, conflict-free RMW.
__global__ __launch_bounds__(256) void k_stats(const float* __restrict__ x,
                                               const int* __restrict__ gt_r,
                                               float* __restrict__ sums,
                                               float* __restrict__ sqs) {
  __shared__ float accS[NC * 256];   // 19456 B
  __shared__ float accQ[NC * 256];   // 19456 B
  int t = threadIdx.x;
  for (int k = t; k < NC * 256; k += 256) { accS[k] = 0.f; accQ[k] = 0.f; }
  __syncthreads();
  int bc = blockIdx.x;               // b*C + c, 256 blocks
  int b = bc >> 6;
  const float4* xp = (const float4*)(x + (size_t)bc * HW);
  const int4*   gp = (const int4*)(gt_r + (size_t)b * HW);
  for (int i = t; i < HW / 4; i += 256) {   // 32 iters/thread, dwordx4 loads
    float4 v = xp[i];
    int4   g = gp[i];
    accS[g.x * 256 + t] += v.x;  accQ[g.x * 256 + t] += v.x * v.x;
    accS[g.y * 256 + t] += v.y;  accQ[g.y * 256 + t] += v.y * v.y;
    accS[g.z * 256 + t] += v.z;  accQ[g.z * 256 + t] += v.z * v.z;
    accS[g.w * 256 + t] += v.w;  accQ[g.w * 256 + t] += v.w * v.w;
  }
  for (int stride = 128; stride >= 1; stride >>= 1) {
    __syncthreads();
    if (t < stride) {
      for (int k = 0; k < NC; k++) {
        accS[k * 256 + t] += accS[k * 256 + t + stride];
        accQ[k * 256 + t] += accQ[k * 256 + t + stride];
      }
    }
  }
  __syncthreads();
  if (t < NC) {
    int c = bc & 63;
    sums[(t * B + b) * C + c] = accS[t * 256];
    sqs [(t * B + b) * C + c] = accQ[t * 256];
  }
}

// ---------------- K3: fold stats -> per-(cid,b,c) scale/shift -----------------------
__global__ __launch_bounds__(256) void k_params(const float* __restrict__ sums,
                                                const float* __restrict__ sqs,
                                                const int* __restrict__ counts,
                                                const float* __restrict__ eps_mu,
                                                const float* __restrict__ eps_std,
                                                float* __restrict__ scale,
                                                float* __restrict__ shift) {
  int idx = blockIdx.x * 256 + threadIdx.x;   // one thread per (cid, c)
  if (idx >= NC * C) return;
  int cid = idx / C;
  int c = idx - cid * C;
  float mean[B], stdv[B];
  float msum = 0.f, ssum = 0.f;
  for (int b = 0; b < B; b++) {
    float cnt = (float)counts[b * NC + cid];
    float n = cnt > 0.f ? cnt : 1.f;          // npx = where(npx==0, 1, npx)
    float s = sums[(cid * B + b) * C + c];
    float q = sqs [(cid * B + b) * C + c];
    float m = s / n;
    float var = q / n - m * m;                // biased (divide by npx), as reference
    var = var > 0.f ? var : 0.f;
    mean[b] = m;
    stdv[b] = sqrtf(var + EPS);
    msum += m; ssum += stdv[b];
  }
  float mbar = msum * 0.25f, sbar = ssum * 0.25f;
  float vm = 0.f, vs = 0.f;
  for (int b = 0; b < B; b++) {
    float dm = mean[b] - mbar; vm += dm * dm;
    float ds = stdv[b] - sbar; vs += ds * ds;
  }
  float sqvm = sqrtf(vm * (1.f / 3.f) + EPS);  // ddof=1 over B=4
  float sqvs = sqrtf(vs * (1.f / 3.f) + EPS);
  for (int b = 0; b < B; b++) {
    int e = (cid * B + b) * C + c;
    float beta  = mean[b] + eps_mu[e]  * sqvm;
    float gamma = stdv[b] + eps_std[e] * sqvs;
    float sc = gamma / stdv[b];
    scale[e] = sc;
    shift[e] = beta - mean[b] * sc;            // out = x*sc + shift
  }
}

// ---------------- K4: apply out = fma(x, scale[cls], shift[cls]) --------------------
__global__ __launch_bounds__(256) void k_apply(const float* __restrict__ x,
                                               const int* __restrict__ gt_r,
                                               const float* __restrict__ scale,
                                               const float* __restrict__ shift,
                                               float* __restrict__ out) {
  __shared__ float2 tab[NC];
  int t = threadIdx.x;
  int plane = blockIdx.x >> 2;     // b*C + c
  int quarter = blockIdx.x & 3;    // 4 blocks per plane -> 1024 blocks
  int b = plane >> 6;
  int c = plane & 63;
  if (t < NC) {
    int e = (t * B + b) * C + c;
    tab[t] = make_float2(scale[e], shift[e]);
  }
  __syncthreads();
  const float4* xp = (const float4*)(x + (size_t)plane * HW) + quarter * 2048;
  const int4*   gp = (const int4*)(gt_r + (size_t)b * HW) + quarter * 2048;
  float4*       op = (float4*)(out + (size_t)plane * HW) + quarter * 2048;
  for (int i = t; i < 2048; i += 256) {      // 8 float4 per thread
    float4 v = xp[i];
    int4   g = gp[i];
    float2 a0 = tab[g.x], a1 = tab[g.y], a2 = tab[g.z], a3 = tab[g.w];
    float4 o;
    o.x = fmaf(v.x, a0.x, a0.y);
    o.y = fmaf(v.y, a1.x, a1.y);
    o.z = fmaf(v.z, a2.x, a2.y);
    o.w = fmaf(v.w, a3.x, a3.y);
    op[i] = o;
  }
}

extern "C" void kernel_launch(void* const* d_in, const int* in_sizes, int n_in,
                              void* d_out, int out_size, void* d_ws, size_t ws_size,
                              hipStream_t stream) {
  const float* x       = (const float*)d_in[0];
  const int*   gt      = (const int*)  d_in[1];
  const float* eps_mu  = (const float*)d_in[2];
  const float* eps_std = (const float*)d_in[3];
  float* out = (float*)d_out;

  // workspace layout (total ~603 KB)
  char* ws = (char*)d_ws;
  int*   gt_r   = (int*)  (ws);            // 131072 ints = 524288 B
  int*   counts = (int*)  (ws + 524288);   // 76 ints
  float* sums   = (float*)(ws + 525312);   // 4864 floats
  float* sqs    = (float*)(ws + 544768);   // 4864 floats
  float* scale  = (float*)(ws + 564224);   // 4864 floats
  float* shift  = (float*)(ws + 583680);   // 4864 floats

  hipMemsetAsync(counts, 0, NC * B * sizeof(int), stream);
  hipLaunchKernelGGL(k_downsample, dim3(B * H), dim3(W), 0, stream, gt, gt_r, counts);
  hipLaunchKernelGGL(k_stats, dim3(B * C), dim3(256), 0, stream, x, gt_r, sums, sqs);
  hipLaunchKernelGGL(k_params, dim3((NC * C + 255) / 256), dim3(256), 0, stream,
                     sums, sqs, counts, eps_mu, eps_std, scale, shift);
  hipLaunchKernelGGL(k_apply, dim3(B * C * 4), dim3(256), 0, stream,
                     x, gt_r, scale, shift, out);
}

// Round 2
// 105.600 us; speedup vs baseline: 1.1809x; 1.1809x over previous
//
#include <hip/hip_runtime.h>

#define EPS 1e-5f
constexpr int B = 4, C = 64, H = 128, W = 256;
constexpr int Hg = 512, Wg = 1024;
constexpr int NC = 19;
constexpr int HW = H * W;      // 32768 pixels per (b,c) plane
constexpr int HW4 = HW / 4;    // 8192 packed-class dwords per batch

// ---------------- K1: downsample gt (stride 4) and pack classes to u8 ---------------
// grid 128 x 256: thread -> 4 gt loads (stride 16B), 1 coalesced dword store.
__global__ __launch_bounds__(256) void k_pack(const int* __restrict__ gt,
                                              unsigned int* __restrict__ gt_p) {
  int t = threadIdx.x;
  int R = blockIdx.x * 4 + (t >> 6);        // global row in [0,512) = b*H + h
  int ws = t & 63;                          // 4-pixel segment within the row
  int b = R >> 7, h = R & 127;
  const int* row = gt + (size_t)(b * Hg + h * 4) * Wg;
  unsigned int c0 = (unsigned int)row[(ws * 4 + 0) * 4];
  unsigned int c1 = (unsigned int)row[(ws * 4 + 1) * 4];
  unsigned int c2 = (unsigned int)row[(ws * 4 + 2) * 4];
  unsigned int c3 = (unsigned int)row[(ws * 4 + 3) * 4];
  gt_p[R * 64 + ws] = c0 | (c1 << 8) | (c2 << 16) | (c3 << 24);
}

// ---------------- K2: per-(b,c,quarter) partial per-class sum/sumsq -----------------
// float2 LDS accumulators acc[cls*256+t]: bank = f(t) only -> conflict-free b64 RMW.
// 1024 blocks (4 per plane) -> 4 blocks/CU (38.9 KB LDS), 16 waves/CU.
__global__ __launch_bounds__(256) void k_stats(const float* __restrict__ x,
                                               const unsigned int* __restrict__ gt_p,
                                               float* __restrict__ sums_p,   // [19*B*C][4]
                                               float* __restrict__ sqs_p,    // [19*B*C][4]
                                               int* __restrict__ counts_p) { // [B*19][4]
  __shared__ float2 acc[NC * 256];   // 38912 B
  __shared__ int hist[NC];
  int t = threadIdx.x;
  for (int k = t; k < NC * 256; k += 256) acc[k] = make_float2(0.f, 0.f);
  int plane = blockIdx.x >> 2;       // b*C + c
  int q = blockIdx.x & 3;
  int b = plane >> 6, c = plane & 63;
  bool desig = (c == 0);             // 16 blocks also build the per-(b,q) histogram
  if (desig && t < NC) hist[t] = 0;
  __syncthreads();

  const float4* xp = (const float4*)x + (size_t)plane * (HW / 4) + q * 2048;
  const unsigned int* gp = gt_p + (size_t)b * HW4 + q * 2048;
  for (int j = 0; j < 8; j++) {
    int i = j * 256 + t;
    float4 v = xp[i];
    unsigned int g = gp[i];
    int c0 = g & 255, c1 = (g >> 8) & 255, c2 = (g >> 16) & 255, c3 = g >> 24;
    float2 a;
    a = acc[c0 * 256 + t]; a.x += v.x; a.y += v.x * v.x; acc[c0 * 256 + t] = a;
    a = acc[c1 * 256 + t]; a.x += v.y; a.y += v.y * v.y; acc[c1 * 256 + t] = a;
    a = acc[c2 * 256 + t]; a.x += v.z; a.y += v.z * v.z; acc[c2 * 256 + t] = a;
    a = acc[c3 * 256 + t]; a.x += v.w; a.y += v.w * v.w; acc[c3 * 256 + t] = a;
    if (desig) {
      atomicAdd(&hist[c0], 1); atomicAdd(&hist[c1], 1);
      atomicAdd(&hist[c2], 1); atomicAdd(&hist[c3], 1);
    }
  }
  __syncthreads();

  // One-barrier reduction: wave w owns classes w, w+4, ... ; 4 LDS reads + shuffle.
  int w = t >> 6, lane = t & 63;
  for (int k = w; k < NC; k += 4) {
    float2 a0 = acc[k * 256 + lane];
    float2 a1 = acc[k * 256 + 64 + lane];
    float2 a2 = acc[k * 256 + 128 + lane];
    float2 a3 = acc[k * 256 + 192 + lane];
    float s  = a0.x + a1.x + a2.x + a3.x;
    float qq = a0.y + a1.y + a2.y + a3.y;
    for (int m = 32; m >= 1; m >>= 1) {
      s  += __shfl_xor(s, m, 64);
      qq += __shfl_xor(qq, m, 64);
    }
    if (lane == 0) {
      int e = (k * B + b) * C + c;
      sums_p[e * 4 + q] = s;
      sqs_p [e * 4 + q] = qq;
    }
  }
  if (desig && t < NC) counts_p[(b * NC + t) * 4 + q] = hist[t];
}

// ---------------- K3+K4 fused: params (threads 0..18) + apply -----------------------
__global__ __launch_bounds__(256) void k_apply(const float* __restrict__ x,
                                               const unsigned int* __restrict__ gt_p,
                                               const float* __restrict__ sums_p,
                                               const float* __restrict__ sqs_p,
                                               const int* __restrict__ counts_p,
                                               const float* __restrict__ eps_mu,
                                               const float* __restrict__ eps_std,
                                               float* __restrict__ out) {
  __shared__ float2 tab[NC];
  int t = threadIdx.x;
  int plane = blockIdx.x >> 2;     // b*C + c
  int q = blockIdx.x & 3;
  int b = plane >> 6, c = plane & 63;
  const float4* xp = (const float4*)x + (size_t)plane * (HW / 4) + q * 2048;
  const unsigned int* gp = gt_p + (size_t)b * HW4 + q * 2048;
  float4* op = (float4*)out + (size_t)plane * (HW / 4) + q * 2048;

  // prefetch tile j=0 while params compute
  float4 v0 = xp[t];
  unsigned int g0 = gp[t];

  if (t < NC) {                    // redundant tiny per-(cid,c) param math
    float mean[B], stdv[B];
    float msum = 0.f, ssum = 0.f;
    for (int bb = 0; bb < B; bb++) {
      int4 cn = *(const int4*)&counts_p[(bb * NC + t) * 4];
      float n = (float)(cn.x + cn.y + cn.z + cn.w);
      if (n == 0.f) n = 1.f;
      float4 s4 = *(const float4*)&sums_p[((t * B + bb) * C + c) * 4];
      float4 q4 = *(const float4*)&sqs_p [((t * B + bb) * C + c) * 4];
      float s  = s4.x + s4.y + s4.z + s4.w;
      float qq = q4.x + q4.y + q4.z + q4.w;
      float m = s / n;
      float var = qq / n - m * m;
      var = var > 0.f ? var : 0.f;
      mean[bb] = m;
      stdv[bb] = sqrtf(var + EPS);
      msum += m; ssum += stdv[bb];
    }
    float mbar = msum * 0.25f, sbar = ssum * 0.25f;
    float vm = 0.f, vs = 0.f;
    for (int bb = 0; bb < B; bb++) {
      float dm = mean[bb] - mbar; vm += dm * dm;
      float ds = stdv[bb] - sbar; vs += ds * ds;
    }
    float sqvm = sqrtf(vm * (1.f / 3.f) + EPS);   // ddof=1 over B=4
    float sqvs = sqrtf(vs * (1.f / 3.f) + EPS);
    int e = (t * B + b) * C + c;
    float beta  = mean[b] + eps_mu[e]  * sqvm;
    float gamma = stdv[b] + eps_std[e] * sqvs;
    float sc = gamma / stdv[b];
    tab[t] = make_float2(sc, beta - mean[b] * sc);  // out = x*sc + shift
  }
  __syncthreads();

  {
    float2 a0 = tab[g0 & 255], a1 = tab[(g0 >> 8) & 255];
    float2 a2 = tab[(g0 >> 16) & 255], a3 = tab[g0 >> 24];
    float4 o;
    o.x = fmaf(v0.x, a0.x, a0.y);
    o.y = fmaf(v0.y, a1.x, a1.y);
    o.z = fmaf(v0.z, a2.x, a2.y);
    o.w = fmaf(v0.w, a3.x, a3.y);
    op[t] = o;
  }
  for (int j = 1; j < 8; j++) {
    int i = j * 256 + t;
    float4 v = xp[i];
    unsigned int g = gp[i];
    float2 a0 = tab[g & 255], a1 = tab[(g >> 8) & 255];
    float2 a2 = tab[(g >> 16) & 255], a3 = tab[g >> 24];
    float4 o;
    o.x = fmaf(v.x, a0.x, a0.y);
    o.y = fmaf(v.y, a1.x, a1.y);
    o.z = fmaf(v.z, a2.x, a2.y);
    o.w = fmaf(v.w, a3.x, a3.y);
    op[i] = o;
  }
}

extern "C" void kernel_launch(void* const* d_in, const int* in_sizes, int n_in,
                              void* d_out, int out_size, void* d_ws, size_t ws_size,
                              hipStream_t stream) {
  const float* x       = (const float*)d_in[0];
  const int*   gt      = (const int*)  d_in[1];
  const float* eps_mu  = (const float*)d_in[2];
  const float* eps_std = (const float*)d_in[3];
  float* out = (float*)d_out;

  // workspace layout (~281 KB, all fully overwritten every call)
  char* ws = (char*)d_ws;
  unsigned int* gt_p    = (unsigned int*)(ws);            // 131072 B packed classes
  float*        sums_p  = (float*)(ws + 131072);          // 19*B*C*4 = 77824 B
  float*        sqs_p   = (float*)(ws + 208896);          // 77824 B
  int*          counts_p= (int*)  (ws + 286720);          // 1216 B

  hipLaunchKernelGGL(k_pack,  dim3(B * H / 4), dim3(256), 0, stream, gt, gt_p);
  hipLaunchKernelGGL(k_stats, dim3(B * C * 4), dim3(256), 0, stream,
                     x, gt_p, sums_p, sqs_p, counts_p);
  hipLaunchKernelGGL(k_apply, dim3(B * C * 4), dim3(256), 0, stream,
                     x, gt_p, sums_p, sqs_p, counts_p, eps_mu, eps_std, out);
}